// Round 3
// baseline (272.571 us; speedup 1.0000x reference)
//
#include <hip/hip_runtime.h>

#define BB 16
#define TT 256
#define NN 2048
#define TC 16                       // t-chunk per block -> grid (8,16,16) = 2048 blocks
#define NREG (BB * (TT / TC))       // 256 private store regions
#define NSLICE 16                   // fallback atomic slices
#define HDR 64                      // scalar header floats
#define COMPACT HDR                 // [13][NN] reduced stats
#define REGION (HDR + 13 * NN)      // region partials: [r][13][NN]

// ws float layout:
//  [3*s + 0..2], s<16 : per-slice (recon_num, temporal_num, nvel) partials
//  [48] identity contrib sum  [49] num_visible  [50] ticket (int)
//  [COMPACT + k*NN + n]                 : reduced per-point stats
//  [REGION + (r*13 + k)*NN + n]         : per-region partials (store or atomic-slice)

__device__ __forceinline__ float waveReduceSum(float v) {
#pragma unroll
  for (int o = 32; o > 0; o >>= 1) v += __shfl_down(v, o, 64);
  return v;
}

template <bool STORE>
__global__ __launch_bounds__(256, 8) void stats_kernel(
    const float* __restrict__ pred, const float* __restrict__ gt,
    const float* __restrict__ vis, float* __restrict__ ws) {
  const int n  = blockIdx.x * 256 + threadIdx.x;
  const int b  = blockIdx.y;
  const int t0 = blockIdx.z * TC;

  const size_t frame0 = (size_t)(b * TT + t0) * NN + n;
  const float3* __restrict__ pp = (const float3*)pred + frame0;
  const float3* __restrict__ gp = (const float3*)gt + frame0;
  const float*  __restrict__ vp = vis + frame0;

  float cnt = 0.f;
  float sp0 = 0, sp1 = 0, sp2 = 0, qp0 = 0, qp1 = 0, qp2 = 0;
  float sg0 = 0, sg1 = 0, sg2 = 0, qg0 = 0, qg1 = 0, qg2 = 0;
  float recon = 0, temporal = 0, nvel = 0;

  // boundary frame t0-1 (velocity only); t0==0 loads frame 0 with mask 0
  float3 ppv, pgv;
  float mprev;
  {
    const long off = (t0 == 0) ? 0 : -(long)NN;
    ppv = pp[off];
    pgv = gp[off];
    float v = vp[off];
    mprev = (t0 != 0 && v > 0.5f) ? 1.f : 0.f;
  }

#pragma unroll
  for (int i = 0; i < TC; ++i) {
    float3 a = pp[(size_t)i * NN];
    float3 g = gp[(size_t)i * NN];
    float v = vp[(size_t)i * NN];
    float m = (v > 0.5f) ? 1.f : 0.f;

    cnt += m;
    sp0 += m * a.x; sp1 += m * a.y; sp2 += m * a.z;
    qp0 += m * a.x * a.x; qp1 += m * a.y * a.y; qp2 += m * a.z * a.z;
    sg0 += m * g.x; sg1 += m * g.y; sg2 += m * g.z;
    qg0 += m * g.x * g.x; qg1 += m * g.y * g.y; qg2 += m * g.z * g.z;
    float d0 = a.x - g.x, d1 = a.y - g.y, d2 = a.z - g.z;
    recon += m * (d0 * d0 + d1 * d1 + 2.f * d2 * d2);

    float mv = m * mprev;
    float vx = (a.x - ppv.x) - (g.x - pgv.x);
    float vy = (a.y - ppv.y) - (g.y - pgv.y);
    float vz = (a.z - ppv.z) - (g.z - pgv.z);
    temporal += mv * (vx * vx + vy * vy + vz * vz);
    nvel += mv;

    ppv = a; pgv = g; mprev = m;
  }

  // per-point partials
  if (STORE) {
    // private region per (b, t-chunk): plain coalesced stores, no RMW
    const int r = b * (TT / TC) + blockIdx.z;
    float* pts = ws + REGION + (size_t)r * 13 * NN + n;
    pts[0 * NN]  = cnt;
    pts[1 * NN]  = sp0;  pts[2 * NN]  = sp1;  pts[3 * NN]  = sp2;
    pts[4 * NN]  = qp0;  pts[5 * NN]  = qp1;  pts[6 * NN]  = qp2;
    pts[7 * NN]  = sg0;  pts[8 * NN]  = sg1;  pts[9 * NN]  = sg2;
    pts[10 * NN] = qg0;  pts[11 * NN] = qg1;  pts[12 * NN] = qg2;
  } else {
    const int r = (b + 2 * blockIdx.z) & (NSLICE - 1);
    float* pts = ws + REGION + (size_t)r * 13 * NN + n;
    atomicAdd(&pts[0 * NN], cnt);
    atomicAdd(&pts[1 * NN], sp0);  atomicAdd(&pts[2 * NN], sp1);
    atomicAdd(&pts[3 * NN], sp2);  atomicAdd(&pts[4 * NN], qp0);
    atomicAdd(&pts[5 * NN], qp1);  atomicAdd(&pts[6 * NN], qp2);
    atomicAdd(&pts[7 * NN], sg0);  atomicAdd(&pts[8 * NN], sg1);
    atomicAdd(&pts[9 * NN], sg2);  atomicAdd(&pts[10 * NN], qg0);
    atomicAdd(&pts[11 * NN], qg1); atomicAdd(&pts[12 * NN], qg2);
  }

  // global scalars: block reduce, one sliced atomic per scalar
  __shared__ float sred[3][4];
  float r0 = waveReduceSum(recon);
  float r1 = waveReduceSum(temporal);
  float r2 = waveReduceSum(nvel);
  int lane = threadIdx.x & 63, w = threadIdx.x >> 6;
  if (lane == 0) { sred[0][w] = r0; sred[1][w] = r1; sred[2][w] = r2; }
  __syncthreads();
  if (threadIdx.x < 3) {
    float s = sred[threadIdx.x][0] + sred[threadIdx.x][1] +
              sred[threadIdx.x][2] + sred[threadIdx.x][3];
    const int slice = (b + 2 * blockIdx.z) & (NSLICE - 1);
    atomicAdd(&ws[slice * 3 + threadIdx.x], s);
  }
}

// sum NR regions into compact [13][NN]; one thread per (k, n); grid = 13*NN/256 = 104
template <int NR>
__global__ __launch_bounds__(256) void reduce_kernel(float* __restrict__ ws) {
  const int idx = blockIdx.x * 256 + threadIdx.x;   // k*NN + n
  const int n = idx & (NN - 1);
  const int k = idx >> 11;
  const float* src = ws + REGION + (size_t)k * NN + n;
  float s0 = 0.f, s1 = 0.f, s2 = 0.f, s3 = 0.f;
#pragma unroll 8
  for (int r = 0; r < NR; r += 4) {
    s0 += src[(size_t)(r + 0) * 13 * NN];
    s1 += src[(size_t)(r + 1) * 13 * NN];
    s2 += src[(size_t)(r + 2) * 13 * NN];
    s3 += src[(size_t)(r + 3) * 13 * NN];
  }
  ws[COMPACT + (size_t)k * NN + n] = (s0 + s1) + (s2 + s3);
}

__global__ __launch_bounds__(256) void identity_final(float* __restrict__ ws,
                                                      float* __restrict__ out) {
  const int n = blockIdx.x * 256 + threadIdx.x;
  float st[13];
#pragma unroll
  for (int k = 0; k < 13; ++k) st[k] = ws[COMPACT + (size_t)k * NN + n];

  float c = st[0];
  float sp0 = st[1], sp1 = st[2], sp2 = st[3];
  float qp0 = st[4], qp1 = st[5], qp2 = st[6];
  float sg0 = st[7], sg1 = st[8], sg2 = st[9];
  float qg0 = st[10], qg1 = st[11], qg2 = st[12];

  float inv = 1.f / fmaxf(c, 1.f);
  float dv  = 1.f / fmaxf(c - 1.f, 1.f);
  float pv0 = (qp0 - sp0 * sp0 * inv) * dv;
  float pv1 = (qp1 - sp1 * sp1 * inv) * dv;
  float pv2 = (qp2 - sp2 * sp2 * inv) * dv;
  float gv0 = (qg0 - sg0 * sg0 * inv) * dv;
  float gv1 = (qg1 - sg1 * sg1 * inv) * dv;
  float gv2 = (qg2 - sg2 * sg2 * inv) * dv;

  float num = fabsf(pv0 - gv0) + fabsf(pv1 - gv1) + fabsf(pv2 - gv2);
  float den = gv0 + gv1 + gv2 + 1e-6f;
  float contrib = (c > 1.f) ? (num / den) : 0.f;

  __shared__ float sred[2][4];
  float r0 = waveReduceSum(contrib);
  float r1 = waveReduceSum(c);
  int lane = threadIdx.x & 63, w = threadIdx.x >> 6;
  if (lane == 0) { sred[0][w] = r0; sred[1][w] = r1; }
  __syncthreads();
  if (threadIdx.x < 2) {
    float s = sred[threadIdx.x][0] + sred[threadIdx.x][1] +
              sred[threadIdx.x][2] + sred[threadIdx.x][3];
    atomicAdd(&ws[48 + threadIdx.x], s);
  }

  // last block (device-scope ticket) runs the epilogue
  __threadfence();
  __shared__ int isLast;
  if (threadIdx.x == 0) {
    int old = atomicAdd((int*)(ws + 50), 1);
    isLast = (old == (int)gridDim.x - 1) ? 1 : 0;
  }
  __syncthreads();
  if (isLast && threadIdx.x < 64) {
    float r = 0.f, t = 0.f, v = 0.f;
    if (lane < NSLICE) {
      r = atomicAdd(&ws[lane * 3 + 0], 0.f);
      t = atomicAdd(&ws[lane * 3 + 1], 0.f);
      v = atomicAdd(&ws[lane * 3 + 2], 0.f);
    }
    r = waveReduceSum(r);
    t = waveReduceSum(t);
    v = waveReduceSum(v);
    if (lane == 0) {
      float idsum = atomicAdd(&ws[48], 0.f);
      float nvis  = atomicAdd(&ws[49], 0.f);
      float recon = (nvis > 0.f) ? r / fmaxf(nvis, 1.f) : 0.f;
      float temporal = (v > 0.f) ? t / fmaxf(v, 1.f) : 0.f;
      float identity = idsum / (float)NN;

      float rl = recon, tl = temporal, il = identity;
      bool all_pos = (rl > 0.f) && (tl > 0.f) && (il > 0.f);
      float maxc = fmaxf(rl, fmaxf(tl, il));
      float target = maxc / 3.f;
      float thresh = 10.f * target;
      float rw = (all_pos && rl > thresh) ? 1.0f * target / fmaxf(rl, 1e-30f) : 1.0f;
      float tw = (all_pos && tl > thresh) ? 0.5f * target / fmaxf(tl, 1e-30f) : 0.5f;
      float iw = (all_pos && il > thresh) ? 0.1f * target / fmaxf(il, 1e-30f) : 0.1f;

      out[0] = rw * recon + tw * temporal + iw * identity;
      out[1] = recon;
      out[2] = temporal;
      out[3] = identity;
    }
  }
}

extern "C" void kernel_launch(void* const* d_in, const int* in_sizes, int n_in,
                              void* d_out, int out_size, void* d_ws, size_t ws_size,
                              hipStream_t stream) {
  const float* pred = (const float*)d_in[0];
  const float* gt   = (const float*)d_in[1];
  const float* vis  = (const float*)d_in[2];
  float* out = (float*)d_out;
  float* ws  = (float*)d_ws;

  dim3 g1(NN / 256, BB, TT / TC);   // (8, 16, 16) = 2048 blocks
  const size_t need_store =
      (size_t)(REGION + (size_t)NREG * 13 * NN) * sizeof(float);   // ~27.4 MB

  if (ws_size >= need_store) {
    // store path: regions written unconditionally -> only header needs zeroing
    hipMemsetAsync(d_ws, 0, HDR * sizeof(float), stream);
    stats_kernel<true><<<g1, 256, 0, stream>>>(pred, gt, vis, ws);
    reduce_kernel<NREG><<<dim3(13 * NN / 256), 256, 0, stream>>>(ws);
  } else {
    // fallback: 16 atomic slices (R2 behavior)
    hipMemsetAsync(d_ws, 0,
                   (size_t)(REGION + (size_t)NSLICE * 13 * NN) * sizeof(float),
                   stream);
    stats_kernel<false><<<g1, 256, 0, stream>>>(pred, gt, vis, ws);
    reduce_kernel<NSLICE><<<dim3(13 * NN / 256), 256, 0, stream>>>(ws);
  }
  identity_final<<<dim3(NN / 256), 256, 0, stream>>>(ws, out);
}

// Round 5
// 253.318 us; speedup vs baseline: 1.0760x; 1.0760x over previous
//
#include <hip/hip_runtime.h>

#define BB 16
#define TT 256
#define NN 2048
#define TC 8                 // frames per block -> grid (8,16,32) = 4096 blocks
#define NSLICE 16            // per-point partial slices
#define HDR 64               // scalar header floats
#define PTS HDR              // [s][13][NN] sliced per-point partials

// ws float layout:
//  [3*s + 0..2], s<16 : per-slice (recon_num, temporal_num, nvel) partials
//  [48] identity contrib sum  [49] num_visible  [50] ticket (int)
//  [PTS + (s*13 + k)*NN + n], s<16, k<13 : cnt, sp0..2, qp0..2, sg0..2, qg0..2

typedef const __attribute__((address_space(1))) void* gas1_t;
typedef __attribute__((address_space(3))) void* las3_t;

__device__ __forceinline__ float waveReduceSum(float v) {
#pragma unroll
  for (int o = 32; o > 0; o >>= 1) v += __shfl_down(v, o, 64);
  return v;
}

__global__ __launch_bounds__(256) void stats_kernel(
    const float* __restrict__ pred, const float* __restrict__ gt,
    const float* __restrict__ vis, float* __restrict__ ws) {
  // sP/sG: [s][256 pts][3] floats. Wave w stages its own 768 B chunk
  // (points w*64..w*64+63) per frame with 48 lanes x 16 B glds -> byte
  // layout is a linear copy, so consumption indexes are unswizzled.
  __shared__ float sP[TC * 768];
  __shared__ float sG[TC * 768];

  const int tid  = threadIdx.x;
  const int w    = tid >> 6;           // wave id
  const int lane = tid & 63;
  const int n0   = blockIdx.x * 256;
  const int b    = blockIdx.y;
  const int t0   = blockIdx.z * TC;
  const int tb   = (t0 == 0) ? 0 : t0 - 1;   // velocity boundary frame

  // ---- regular VGPR loads: boundary pred/gt/vis + vis for all TC frames ----
  const size_t elemB = (size_t)(b * TT + tb) * NN + n0 + tid;
  float3 ab = *(const float3*)(pred + elemB * 3);
  float3 gb = *(const float3*)(gt   + elemB * 3);
  float  vb = vis[elemB];

  const size_t elem0 = (size_t)(b * TT + t0) * NN + n0 + tid;
  float vv[TC];
#pragma unroll
  for (int s = 0; s < TC; ++s) vv[s] = vis[elem0 + (size_t)s * NN];

  // drain regular loads so vmcnt below counts ONLY the staged glds
  asm volatile("s_waitcnt vmcnt(0)" ::: "memory");
  __builtin_amdgcn_sched_barrier(0);

  // boundary velocity state (error-form: vel diff = e_t - e_{t-1})
  float mprev = (t0 != 0 && vb > 0.5f) ? 1.f : 0.f;
  float epx = ab.x - gb.x, epy = ab.y - gb.y, epz = ab.z - gb.z;

  // ---- issue 2*TC async global->LDS stages (16 B/lane, 48 active lanes) ----
  // source: block frame base + w*768 B + lane*16 B (per-lane); dest: wave-
  // uniform LDS base + lane*16 B (HW rule). Lanes 48..63 are exec-masked off.
  {
    const size_t fbase = ((size_t)(b * TT + t0) * NN + n0) * 3;  // floats
    const float* pf = pred + fbase + w * 192 + lane * 4;
    const float* gf = gt   + fbase + w * 192 + lane * 4;
    if (lane < 48) {
#pragma unroll
      for (int s = 0; s < TC; ++s) {
        __builtin_amdgcn_global_load_lds((gas1_t)(pf + (size_t)s * NN * 3),
                                         (las3_t)&sP[s * 768 + w * 192], 16, 0, 0);
        __builtin_amdgcn_global_load_lds((gas1_t)(gf + (size_t)s * NN * 3),
                                         (las3_t)&sG[s * 768 + w * 192], 16, 0, 0);
      }
    }
  }

  float cnt = 0.f;
  float sp0 = 0, sp1 = 0, sp2 = 0, qp0 = 0, qp1 = 0, qp2 = 0;
  float sg0 = 0, sg1 = 0, sg2 = 0, qg0 = 0, qg1 = 0, qg2 = 0;
  float recon = 0, temporal = 0, nvel = 0;

  // ---- consume with counted vmcnt: frame s needs glds pairs 0..s done ----
  // vmcnt completes in order; each wave waits only on its own counter,
  // reads only its own LDS chunk -> no barriers anywhere in the loop.
#pragma unroll
  for (int s = 0; s < TC; ++s) {
    asm volatile("s_waitcnt vmcnt(%0)" :: "i"(2 * TC - 2 - 2 * s) : "memory");
    __builtin_amdgcn_sched_barrier(0);
    float3 a = *(const float3*)&sP[s * 768 + tid * 3];
    float3 g = *(const float3*)&sG[s * 768 + tid * 3];
    float m = (vv[s] > 0.5f) ? 1.f : 0.f;

    float ex = a.x - g.x, ey = a.y - g.y, ez = a.z - g.z;
    cnt += m;
    sp0 += m * a.x; sp1 += m * a.y; sp2 += m * a.z;
    qp0 += m * a.x * a.x; qp1 += m * a.y * a.y; qp2 += m * a.z * a.z;
    sg0 += m * g.x; sg1 += m * g.y; sg2 += m * g.z;
    qg0 += m * g.x * g.x; qg1 += m * g.y * g.y; qg2 += m * g.z * g.z;
    recon += m * (ex * ex + ey * ey + 2.f * ez * ez);

    float mv = m * mprev;
    float dx = ex - epx, dy = ey - epy, dz = ez - epz;
    temporal += mv * (dx * dx + dy * dy + dz * dz);
    nvel += mv;

    epx = ex; epy = ey; epz = ez; mprev = m;
  }

  // ---- per-point partials: 16-slice atomics (proven non-bottleneck) ----
  const int slice = (b + blockIdx.z) & (NSLICE - 1);
  float* pts = ws + PTS + (size_t)slice * 13 * NN;
  const int n = n0 + tid;
  atomicAdd(&pts[0 * NN + n], cnt);
  atomicAdd(&pts[1 * NN + n], sp0);
  atomicAdd(&pts[2 * NN + n], sp1);
  atomicAdd(&pts[3 * NN + n], sp2);
  atomicAdd(&pts[4 * NN + n], qp0);
  atomicAdd(&pts[5 * NN + n], qp1);
  atomicAdd(&pts[6 * NN + n], qp2);
  atomicAdd(&pts[7 * NN + n], sg0);
  atomicAdd(&pts[8 * NN + n], sg1);
  atomicAdd(&pts[9 * NN + n], sg2);
  atomicAdd(&pts[10 * NN + n], qg0);
  atomicAdd(&pts[11 * NN + n], qg1);
  atomicAdd(&pts[12 * NN + n], qg2);

  // ---- scalar partials: block reduce, one sliced atomic per scalar ----
  __shared__ float sred[3][4];
  float r0 = waveReduceSum(recon);
  float r1 = waveReduceSum(temporal);
  float r2 = waveReduceSum(nvel);
  if (lane == 0) { sred[0][w] = r0; sred[1][w] = r1; sred[2][w] = r2; }
  __syncthreads();
  if (tid < 3) {
    float s = sred[tid][0] + sred[tid][1] + sred[tid][2] + sred[tid][3];
    atomicAdd(&ws[slice * 3 + tid], s);
  }
}

__global__ __launch_bounds__(256) void identity_final(float* __restrict__ ws,
                                                      float* __restrict__ out) {
  const int n = blockIdx.x * 256 + threadIdx.x;
  const float* base = ws + PTS;
  float st[13];
#pragma unroll
  for (int k = 0; k < 13; ++k) st[k] = 0.f;
#pragma unroll
  for (int s = 0; s < NSLICE; ++s) {
#pragma unroll
    for (int k = 0; k < 13; ++k) st[k] += base[(size_t)(s * 13 + k) * NN + n];
  }
  float c = st[0];
  float sp0 = st[1], sp1 = st[2], sp2 = st[3];
  float qp0 = st[4], qp1 = st[5], qp2 = st[6];
  float sg0 = st[7], sg1 = st[8], sg2 = st[9];
  float qg0 = st[10], qg1 = st[11], qg2 = st[12];

  float inv = 1.f / fmaxf(c, 1.f);
  float dv  = 1.f / fmaxf(c - 1.f, 1.f);
  float pv0 = (qp0 - sp0 * sp0 * inv) * dv;
  float pv1 = (qp1 - sp1 * sp1 * inv) * dv;
  float pv2 = (qp2 - sp2 * sp2 * inv) * dv;
  float gv0 = (qg0 - sg0 * sg0 * inv) * dv;
  float gv1 = (qg1 - sg1 * sg1 * inv) * dv;
  float gv2 = (qg2 - sg2 * sg2 * inv) * dv;

  float num = fabsf(pv0 - gv0) + fabsf(pv1 - gv1) + fabsf(pv2 - gv2);
  float den = gv0 + gv1 + gv2 + 1e-6f;
  float contrib = (c > 1.f) ? (num / den) : 0.f;

  __shared__ float sred[2][4];
  float r0 = waveReduceSum(contrib);
  float r1 = waveReduceSum(c);
  int lane = threadIdx.x & 63, w = threadIdx.x >> 6;
  if (lane == 0) { sred[0][w] = r0; sred[1][w] = r1; }
  __syncthreads();
  if (threadIdx.x < 2) {
    float s = sred[threadIdx.x][0] + sred[threadIdx.x][1] +
              sred[threadIdx.x][2] + sred[threadIdx.x][3];
    atomicAdd(&ws[48 + threadIdx.x], s);
  }

  // last block (device-scope ticket) runs the epilogue
  __threadfence();
  __shared__ int isLast;
  if (threadIdx.x == 0) {
    int old = atomicAdd((int*)(ws + 50), 1);
    isLast = (old == (int)gridDim.x - 1) ? 1 : 0;
  }
  __syncthreads();
  if (isLast && threadIdx.x < 64) {
    float r = 0.f, t = 0.f, v = 0.f;
    if (lane < NSLICE) {
      r = atomicAdd(&ws[lane * 3 + 0], 0.f);
      t = atomicAdd(&ws[lane * 3 + 1], 0.f);
      v = atomicAdd(&ws[lane * 3 + 2], 0.f);
    }
    r = waveReduceSum(r);
    t = waveReduceSum(t);
    v = waveReduceSum(v);
    if (lane == 0) {
      float idsum = atomicAdd(&ws[48], 0.f);
      float nvis  = atomicAdd(&ws[49], 0.f);
      float recon = (nvis > 0.f) ? r / fmaxf(nvis, 1.f) : 0.f;
      float temporal = (v > 0.f) ? t / fmaxf(v, 1.f) : 0.f;
      float identity = idsum / (float)NN;

      float rl = recon, tl = temporal, il = identity;
      bool all_pos = (rl > 0.f) && (tl > 0.f) && (il > 0.f);
      float maxc = fmaxf(rl, fmaxf(tl, il));
      float target = maxc / 3.f;
      float thresh = 10.f * target;
      float rw = (all_pos && rl > thresh) ? 1.0f * target / fmaxf(rl, 1e-30f) : 1.0f;
      float tw = (all_pos && tl > thresh) ? 0.5f * target / fmaxf(tl, 1e-30f) : 0.5f;
      float iw = (all_pos && il > thresh) ? 0.1f * target / fmaxf(il, 1e-30f) : 0.1f;

      out[0] = rw * recon + tw * temporal + iw * identity;
      out[1] = recon;
      out[2] = temporal;
      out[3] = identity;
    }
  }
}

extern "C" void kernel_launch(void* const* d_in, const int* in_sizes, int n_in,
                              void* d_out, int out_size, void* d_ws, size_t ws_size,
                              hipStream_t stream) {
  const float* pred = (const float*)d_in[0];
  const float* gt   = (const float*)d_in[1];
  const float* vis  = (const float*)d_in[2];
  float* out = (float*)d_out;
  float* ws  = (float*)d_ws;

  hipMemsetAsync(d_ws, 0,
                 (size_t)(HDR + (size_t)NSLICE * 13 * NN) * sizeof(float),
                 stream);

  dim3 g1(NN / 256, BB, TT / TC);   // (8, 16, 32) = 4096 blocks
  stats_kernel<<<g1, 256, 0, stream>>>(pred, gt, vis, ws);
  identity_final<<<dim3(NN / 256), 256, 0, stream>>>(ws, out);
}

// Round 6
// 235.702 us; speedup vs baseline: 1.1564x; 1.0747x over previous
//
#include <hip/hip_runtime.h>

#define BB 16
#define TT 256
#define NN 2048
#define TC 16            // t-chunk per block -> grid (8,16,16) = 2048 blocks
#define NSLICE 16        // per-point partial slices
#define HDR 64           // scalar header floats
#define PTS HDR          // [s][13][NN] sliced per-point partials

// ws float layout:
//  [3*s + 0..2], s<16 : per-slice (recon_num, temporal_num, nvel) partials
//  [48] identity contrib sum  [49] num_visible  [50] ticket (int)
//  [PTS + (s*13 + k)*NN + n], s<16, k<13 : cnt, sp0..2, qp0..2, sg0..2, qg0..2

__device__ __forceinline__ float waveReduceSum(float v) {
#pragma unroll
  for (int o = 32; o > 0; o >>= 1) v += __shfl_down(v, o, 64);
  return v;
}

// nontemporal (no-allocate) 3-float load; adjacent scalars merge to dwordx3 nt
__device__ __forceinline__ float3 ntload3(const float* p) {
  float3 r;
  r.x = __builtin_nontemporal_load(p);
  r.y = __builtin_nontemporal_load(p + 1);
  r.z = __builtin_nontemporal_load(p + 2);
  return r;
}

__global__ __launch_bounds__(256, 8) void stats_kernel(
    const float* __restrict__ pred, const float* __restrict__ gt,
    const float* __restrict__ vis, float* __restrict__ ws) {
  const int n  = blockIdx.x * 256 + threadIdx.x;
  const int b  = blockIdx.y;
  const int t0 = blockIdx.z * TC;

  const size_t frame0 = (size_t)(b * TT + t0) * NN + n;
  const float* __restrict__ pp = pred + frame0 * 3;   // float elements
  const float* __restrict__ gp = gt   + frame0 * 3;
  const float* __restrict__ vp = vis  + frame0;

  float cnt = 0.f;
  float sp0 = 0, sp1 = 0, sp2 = 0, qp0 = 0, qp1 = 0, qp2 = 0;
  float sg0 = 0, sg1 = 0, sg2 = 0, qg0 = 0, qg1 = 0, qg2 = 0;
  float recon = 0, temporal = 0, nvel = 0;

  // boundary frame t0-1 (velocity only); t0==0 loads frame 0 with mask 0
  float3 ppv, pgv;
  float mprev;
  {
    const long offe = (t0 == 0) ? 0 : -(long)NN * 3;
    const long offv = (t0 == 0) ? 0 : -(long)NN;
    ppv = ntload3(pp + offe);
    pgv = ntload3(gp + offe);
    float v = __builtin_nontemporal_load(vp + offv);
    mprev = (t0 != 0 && v > 0.5f) ? 1.f : 0.f;
  }

#pragma unroll
  for (int i = 0; i < TC; ++i) {
    float3 a = ntload3(pp + (size_t)i * NN * 3);
    float3 g = ntload3(gp + (size_t)i * NN * 3);
    float v = __builtin_nontemporal_load(vp + (size_t)i * NN);
    float m = (v > 0.5f) ? 1.f : 0.f;

    cnt += m;
    sp0 += m * a.x; sp1 += m * a.y; sp2 += m * a.z;
    qp0 += m * a.x * a.x; qp1 += m * a.y * a.y; qp2 += m * a.z * a.z;
    sg0 += m * g.x; sg1 += m * g.y; sg2 += m * g.z;
    qg0 += m * g.x * g.x; qg1 += m * g.y * g.y; qg2 += m * g.z * g.z;
    float d0 = a.x - g.x, d1 = a.y - g.y, d2 = a.z - g.z;
    recon += m * (d0 * d0 + d1 * d1 + 2.f * d2 * d2);

    float mv = m * mprev;
    float vx = (a.x - ppv.x) - (g.x - pgv.x);
    float vy = (a.y - ppv.y) - (g.y - pgv.y);
    float vz = (a.z - ppv.z) - (g.z - pgv.z);
    temporal += mv * (vx * vx + vy * vy + vz * vz);
    nvel += mv;

    ppv = a; pgv = g; mprev = m;
  }

  // per-point partials: 16-slice atomics (proven non-bottleneck)
  const int slice = (b + blockIdx.z) & (NSLICE - 1);
  float* pts = ws + PTS + (size_t)slice * 13 * NN;
  atomicAdd(&pts[0 * NN + n], cnt);
  atomicAdd(&pts[1 * NN + n], sp0);
  atomicAdd(&pts[2 * NN + n], sp1);
  atomicAdd(&pts[3 * NN + n], sp2);
  atomicAdd(&pts[4 * NN + n], qp0);
  atomicAdd(&pts[5 * NN + n], qp1);
  atomicAdd(&pts[6 * NN + n], qp2);
  atomicAdd(&pts[7 * NN + n], sg0);
  atomicAdd(&pts[8 * NN + n], sg1);
  atomicAdd(&pts[9 * NN + n], sg2);
  atomicAdd(&pts[10 * NN + n], qg0);
  atomicAdd(&pts[11 * NN + n], qg1);
  atomicAdd(&pts[12 * NN + n], qg2);

  // scalar partials: block reduce, one sliced atomic per scalar
  __shared__ float sred[3][4];
  float r0 = waveReduceSum(recon);
  float r1 = waveReduceSum(temporal);
  float r2 = waveReduceSum(nvel);
  int lane = threadIdx.x & 63, w = threadIdx.x >> 6;
  if (lane == 0) { sred[0][w] = r0; sred[1][w] = r1; sred[2][w] = r2; }
  __syncthreads();
  if (threadIdx.x < 3) {
    float s = sred[threadIdx.x][0] + sred[threadIdx.x][1] +
              sred[threadIdx.x][2] + sred[threadIdx.x][3];
    atomicAdd(&ws[slice * 3 + threadIdx.x], s);
  }
}

__global__ __launch_bounds__(256) void identity_final(float* __restrict__ ws,
                                                      float* __restrict__ out) {
  const int n = blockIdx.x * 256 + threadIdx.x;
  const float* base = ws + PTS;
  float st[13];
#pragma unroll
  for (int k = 0; k < 13; ++k) st[k] = 0.f;
#pragma unroll
  for (int s = 0; s < NSLICE; ++s) {
#pragma unroll
    for (int k = 0; k < 13; ++k) st[k] += base[(size_t)(s * 13 + k) * NN + n];
  }
  float c = st[0];
  float sp0 = st[1], sp1 = st[2], sp2 = st[3];
  float qp0 = st[4], qp1 = st[5], qp2 = st[6];
  float sg0 = st[7], sg1 = st[8], sg2 = st[9];
  float qg0 = st[10], qg1 = st[11], qg2 = st[12];

  float inv = 1.f / fmaxf(c, 1.f);
  float dv  = 1.f / fmaxf(c - 1.f, 1.f);
  float pv0 = (qp0 - sp0 * sp0 * inv) * dv;
  float pv1 = (qp1 - sp1 * sp1 * inv) * dv;
  float pv2 = (qp2 - sp2 * sp2 * inv) * dv;
  float gv0 = (qg0 - sg0 * sg0 * inv) * dv;
  float gv1 = (qg1 - sg1 * sg1 * inv) * dv;
  float gv2 = (qg2 - sg2 * sg2 * inv) * dv;

  float num = fabsf(pv0 - gv0) + fabsf(pv1 - gv1) + fabsf(pv2 - gv2);
  float den = gv0 + gv1 + gv2 + 1e-6f;
  float contrib = (c > 1.f) ? (num / den) : 0.f;

  __shared__ float sred[2][4];
  float r0 = waveReduceSum(contrib);
  float r1 = waveReduceSum(c);
  int lane = threadIdx.x & 63, w = threadIdx.x >> 6;
  if (lane == 0) { sred[0][w] = r0; sred[1][w] = r1; }
  __syncthreads();
  if (threadIdx.x < 2) {
    float s = sred[threadIdx.x][0] + sred[threadIdx.x][1] +
              sred[threadIdx.x][2] + sred[threadIdx.x][3];
    atomicAdd(&ws[48 + threadIdx.x], s);
  }

  // last block (device-scope ticket) runs the epilogue
  __threadfence();
  __shared__ int isLast;
  if (threadIdx.x == 0) {
    int old = atomicAdd((int*)(ws + 50), 1);
    isLast = (old == (int)gridDim.x - 1) ? 1 : 0;
  }
  __syncthreads();
  if (isLast && threadIdx.x < 64) {
    float r = 0.f, t = 0.f, v = 0.f;
    if (lane < NSLICE) {
      r = atomicAdd(&ws[lane * 3 + 0], 0.f);
      t = atomicAdd(&ws[lane * 3 + 1], 0.f);
      v = atomicAdd(&ws[lane * 3 + 2], 0.f);
    }
    r = waveReduceSum(r);
    t = waveReduceSum(t);
    v = waveReduceSum(v);
    if (lane == 0) {
      float idsum = atomicAdd(&ws[48], 0.f);
      float nvis  = atomicAdd(&ws[49], 0.f);
      float recon = (nvis > 0.f) ? r / fmaxf(nvis, 1.f) : 0.f;
      float temporal = (v > 0.f) ? t / fmaxf(v, 1.f) : 0.f;
      float identity = idsum / (float)NN;

      float rl = recon, tl = temporal, il = identity;
      bool all_pos = (rl > 0.f) && (tl > 0.f) && (il > 0.f);
      float maxc = fmaxf(rl, fmaxf(tl, il));
      float target = maxc / 3.f;
      float thresh = 10.f * target;
      float rw = (all_pos && rl > thresh) ? 1.0f * target / fmaxf(rl, 1e-30f) : 1.0f;
      float tw = (all_pos && tl > thresh) ? 0.5f * target / fmaxf(tl, 1e-30f) : 0.5f;
      float iw = (all_pos && il > thresh) ? 0.1f * target / fmaxf(il, 1e-30f) : 0.1f;

      out[0] = rw * recon + tw * temporal + iw * identity;
      out[1] = recon;
      out[2] = temporal;
      out[3] = identity;
    }
  }
}

extern "C" void kernel_launch(void* const* d_in, const int* in_sizes, int n_in,
                              void* d_out, int out_size, void* d_ws, size_t ws_size,
                              hipStream_t stream) {
  const float* pred = (const float*)d_in[0];
  const float* gt   = (const float*)d_in[1];
  const float* vis  = (const float*)d_in[2];
  float* out = (float*)d_out;
  float* ws  = (float*)d_ws;

  hipMemsetAsync(d_ws, 0,
                 (size_t)(HDR + (size_t)NSLICE * 13 * NN) * sizeof(float),
                 stream);

  dim3 g1(NN / 256, BB, TT / TC);   // (8, 16, 16) = 2048 blocks
  stats_kernel<<<g1, 256, 0, stream>>>(pred, gt, vis, ws);
  identity_final<<<dim3(NN / 256), 256, 0, stream>>>(ws, out);
}